// Round 4
// baseline (81.633 us; speedup 1.0000x reference)
//
#include <hip/hip_runtime.h>

#define NROWS 8192
#define NCOLS 4096
#define LAMB  0.1

// ---------------------------------------------------------------------------
// Kernel 1: per-row squared error sum. ONE WAVE PER ROW. (unchanged, memory-
// system bound: 268 MB reads, ~half served by L3.)
// ---------------------------------------------------------------------------
__global__ __launch_bounds__(256) void rowerr_kernel(const float* __restrict__ inp,
                                                     const float* __restrict__ tgt,
                                                     float* __restrict__ err) {
    const int lane = threadIdx.x & 63;
    const int wv   = threadIdx.x >> 6;
    const int row  = blockIdx.x * 4 + wv;

    const float4* a = reinterpret_cast<const float4*>(inp + (size_t)row * NCOLS);
    const float4* b = reinterpret_cast<const float4*>(tgt + (size_t)row * NCOLS);

    float acc0 = 0.f, acc1 = 0.f, acc2 = 0.f, acc3 = 0.f;
#pragma unroll
    for (int c = 0; c < 16; ++c) {
        const float4 va = a[lane + c * 64];
        const float4 vb = b[lane + c * 64];
        const float dx = va.x - vb.x;
        const float dy = va.y - vb.y;
        const float dz = va.z - vb.z;
        const float dw = va.w - vb.w;
        acc0 += dx * dx;
        acc1 += dy * dy;
        acc2 += dz * dz;
        acc3 += dw * dw;
    }
    float acc = (acc0 + acc1) + (acc2 + acc3);

#pragma unroll
    for (int off = 32; off > 0; off >>= 1) acc += __shfl_down(acc, off, 64);

    if (lane == 0) err[row] = acc;
}

// ---------------------------------------------------------------------------
// Kernel 2: rank-and-scatter "sort" spread over 128 CUs.
// Block b owns elements i = b*64 + lane (64 elems/block). Each of the 16
// waves counts comparisons against a 512-element j-slice of the LDS-resident
// err array (broadcast reads). Stable rank = #{e_j < e_i} + #{e_j==e_i, j<i}
// is an exact permutation even with duplicates. Wave 0 combines partials and
// scatters e_i to sorted[rank].
// ---------------------------------------------------------------------------
__global__ __launch_bounds__(1024) void rank_kernel(const float* __restrict__ err,
                                                    float* __restrict__ sorted) {
    __shared__ float se[NROWS];          // 32 KB
    __shared__ int   part[16 * 64];

    const int tid  = threadIdx.x;
    const int lane = tid & 63, wv = tid >> 6;

    {   // stage err -> LDS (vectorized)
        const float4* e4 = reinterpret_cast<const float4*>(err);
        float4* s4 = reinterpret_cast<float4*>(se);
        for (int i = tid; i < NROWS / 4; i += 1024) s4[i] = e4[i];
    }
    __syncthreads();

    const int   i  = blockIdx.x * 64 + lane;
    const float ei = se[i];

    int cnt = 0;
    const int j0 = wv * 512;
#pragma unroll 8
    for (int j = 0; j < 512; ++j) {
        const int   jg = j0 + j;
        const float ej = se[jg];             // same addr across lanes: broadcast
        cnt += (ej < ei) ? 1 : 0;
        cnt += (ej == ei && jg < i) ? 1 : 0; // stable tie-break
    }
    part[wv * 64 + lane] = cnt;
    __syncthreads();

    if (wv == 0) {
        int rank = 0;
#pragma unroll
        for (int w = 0; w < 16; ++w) rank += part[w * 64 + lane];
        sorted[rank] = ei;
    }
}

// ---------------------------------------------------------------------------
// fast f64 reciprocal: f32 seed + 2 Newton steps (~1 ulp, no f64 divide)
// ---------------------------------------------------------------------------
__device__ __forceinline__ double fastrcp(double x) {
    double r = (double)(1.0f / (float)x);
    r = r * (2.0 - x * r);
    r = r * (2.0 - x * r);
    return r;
}

// ---------------------------------------------------------------------------
// Kernel 3: single block, 1024 threads, NO SORT (input already sorted).
// f64 scan of cs only; total2 via block reduce. Objective reformulated:
//   argmin (Sw1+Sw2)/Sb  ==  argmax h(k) = cs_k^2/k + (total-cs_k)^2/(n-k)
// (total2 terms are constant, Sb > 0). No per-element divisions.
// ---------------------------------------------------------------------------
__global__ __launch_bounds__(1024) void obj_kernel(const float* __restrict__ sorted,
                                                   float* __restrict__ out) {
    const int N = NROWS;
    __shared__ double auxX[16], auxT2[16];
    __shared__ double redH[16], redCs[16];
    __shared__ int    redIdx[16];

    const int tid = threadIdx.x;
    const int lane = tid & 63, wv = tid >> 6;

    float v[8];
    {
        const float4* s4 = reinterpret_cast<const float4*>(sorted);
        float4 a = s4[tid * 2];
        float4 b = s4[tid * 2 + 1];
        v[0] = a.x; v[1] = a.y; v[2] = a.z; v[3] = a.w;
        v[4] = b.x; v[5] = b.y; v[6] = b.z; v[7] = b.w;
    }

    double sx = 0.0, sx2 = 0.0;
#pragma unroll
    for (int r = 0; r < 8; ++r) {
        sx  += (double)v[r];
        sx2 += (double)v[r] * (double)v[r];
    }

    // wave inclusive scan of sx; wave total of sx2
    double ix = sx;
#pragma unroll
    for (int off = 1; off < 64; off <<= 1) {
        double t1 = __shfl_up(ix, off, 64);
        if (lane >= off) ix += t1;
    }
    double t2 = sx2;
#pragma unroll
    for (int off = 32; off > 0; off >>= 1) t2 += __shfl_xor(t2, off, 64);

    if (lane == 63) auxX[wv]  = ix;
    if (lane == 0)  auxT2[wv] = t2;
    __syncthreads();

    double wOff1 = 0.0, total1 = 0.0, total2 = 0.0;
#pragma unroll
    for (int w = 0; w < 16; ++w) {
        const double a1 = auxX[w];
        if (w < wv) wOff1 += a1;
        total1 += a1;
        total2 += auxT2[w];
    }
    const double exc1 = wOff1 + (ix - sx);   // exclusive prefix before this chunk
    const double nf = (double)N;

    // on-the-fly h(k) evaluation + local argmax (== argmin obj), first idx on tie
    double run1 = exc1;
    double bestH = -1e300, bestCs = 0.0;
    int bestIdx = N;
#pragma unroll
    for (int r = 0; r < 8; ++r) {
        const int idx = (tid << 3) + r;
        run1 += (double)v[r];
        if (idx < N - 1) {
            const double kf  = (double)(idx + 1);
            const double rem = total1 - run1;
            const double h   = run1 * run1 * fastrcp(kf) +
                               rem  * rem  * fastrcp(nf - kf);
            if (h > bestH) { bestH = h; bestIdx = idx; bestCs = run1; }
        }
    }

    // wave argmax reduce (max h, first index on ties)
#pragma unroll
    for (int off = 32; off > 0; off >>= 1) {
        const double oH   = __shfl_down(bestH, off, 64);
        const int    oIdx = __shfl_down(bestIdx, off, 64);
        const double oCs  = __shfl_down(bestCs, off, 64);
        if (oH > bestH || (oH == bestH && oIdx < bestIdx)) {
            bestH = oH; bestIdx = oIdx; bestCs = oCs;
        }
    }
    if (lane == 0) { redH[wv] = bestH; redIdx[wv] = bestIdx; redCs[wv] = bestCs; }
    __syncthreads();

    if (tid == 0) {
        double bH = redH[0], bCs = redCs[0];
        int bIdx = redIdx[0];
        for (int w = 1; w < 16; ++w) {
            if (redH[w] > bH || (redH[w] == bH && redIdx[w] < bIdx)) {
                bH = redH[w]; bIdx = redIdx[w]; bCs = redCs[w];
            }
        }
        const double Sb     = total2 - total1 * total1 / nf;
        const double optObj = (total2 - bH) / Sb;
        const double T      = (double)(bIdx + 1);
        out[0] = (float)(bCs / T + LAMB * optObj);
    }
}

// ---------------------------------------------------------------------------
extern "C" void kernel_launch(void* const* d_in, const int* in_sizes, int n_in,
                              void* d_out, int out_size, void* d_ws, size_t ws_size,
                              hipStream_t stream) {
    const float* inp = (const float*)d_in[0];
    const float* tgt = (const float*)d_in[1];
    float* errbuf    = (float*)d_ws;                 // 8192 f32
    float* sortedbuf = (float*)d_ws + NROWS;         // 8192 f32

    rowerr_kernel<<<NROWS / 4, 256, 0, stream>>>(inp, tgt, errbuf);
    rank_kernel<<<NROWS / 64, 1024, 0, stream>>>(errbuf, sortedbuf);
    obj_kernel<<<1, 1024, 0, stream>>>(sortedbuf, (float*)d_out);
}

// Round 5
// 74.576 us; speedup vs baseline: 1.0946x; 1.0946x over previous
//
#include <hip/hip_runtime.h>

#define NROWS 8192
#define NCOLS 4096
#define LAMB  0.1

// ---------------------------------------------------------------------------
// Kernel 1: per-row squared error sum. One wave per 2 rows, 4096 waves total
// = 16 waves/CU in a SINGLE residency round (launch_bounds(256,4)).
// Loads batched into register arrays (8 float4 per stream) BEFORE any FMA:
// ~16 KB in flight per wave to hide HBM latency.
// ---------------------------------------------------------------------------
__global__ __launch_bounds__(256, 4) void rowerr_kernel(const float* __restrict__ inp,
                                                        const float* __restrict__ tgt,
                                                        float* __restrict__ err) {
    const int lane = threadIdx.x & 63;
    const int wid  = blockIdx.x * 4 + (threadIdx.x >> 6);   // 0..4095

#pragma unroll
    for (int rr = 0; rr < 2; ++rr) {
        const int row = wid * 2 + rr;
        const float4* a = reinterpret_cast<const float4*>(inp + (size_t)row * NCOLS);
        const float4* b = reinterpret_cast<const float4*>(tgt + (size_t)row * NCOLS);

        float acc0 = 0.f, acc1 = 0.f, acc2 = 0.f, acc3 = 0.f;
#pragma unroll
        for (int half = 0; half < 2; ++half) {
            float4 va[8], vb[8];
#pragma unroll
            for (int c = 0; c < 8; ++c) va[c] = a[lane + (half * 8 + c) * 64];
#pragma unroll
            for (int c = 0; c < 8; ++c) vb[c] = b[lane + (half * 8 + c) * 64];
#pragma unroll
            for (int c = 0; c < 8; ++c) {
                const float dx = va[c].x - vb[c].x;
                const float dy = va[c].y - vb[c].y;
                const float dz = va[c].z - vb[c].z;
                const float dw = va[c].w - vb[c].w;
                acc0 += dx * dx;
                acc1 += dy * dy;
                acc2 += dz * dz;
                acc3 += dw * dw;
            }
        }
        float acc = (acc0 + acc1) + (acc2 + acc3);

#pragma unroll
        for (int off = 32; off > 0; off >>= 1) acc += __shfl_down(acc, off, 64);

        if (lane == 0) err[row] = acc;
    }
}

// ---------------------------------------------------------------------------
// fast f64 reciprocal: f32 seed + 2 Newton steps (~1 ulp, no f64 divide)
// ---------------------------------------------------------------------------
__device__ __forceinline__ double fastrcp(double x) {
    double r = (double)(1.0f / (float)x);
    r = r * (2.0 - x * r);
    r = r * (2.0 - x * r);
    return r;
}

// ---------------------------------------------------------------------------
// Kernel 2: single block, 1024 threads, 8 elements/thread IN REGISTERS.
// Hybrid bitonic sort (register / shuffle / LDS passes), then f64 scan of cs
// and block-total of cs2, then argmax of
//   h(k) = cs_k^2/k + (total-cs_k)^2/(n-k)
// which equals argmin (Sw1+Sw2)/Sb (total2 terms constant, Sb>0).
// ---------------------------------------------------------------------------
__global__ __launch_bounds__(1024) void drae_kernel(const float* __restrict__ err,
                                                    float* __restrict__ out) {
    const int N = NROWS;
    __shared__ float s[NROWS];        // 32 KB, used only for cross-wave passes
    __shared__ double auxX[16], auxT2[16];
    __shared__ double redH[16], redCs[16];
    __shared__ int    redIdx[16];

    const int tid = threadIdx.x;
    const int lane = tid & 63, wv = tid >> 6;

    // load 8 contiguous elements into registers (two float4)
    float v[8];
    {
        const float4* e4 = reinterpret_cast<const float4*>(err);
        float4 a = e4[tid * 2];
        float4 b = e4[tid * 2 + 1];
        v[0] = a.x; v[1] = a.y; v[2] = a.z; v[3] = a.w;
        v[4] = b.x; v[5] = b.y; v[6] = b.z; v[7] = b.w;
    }

#define CEPAIR(ra, rb)                                                \
    {                                                                 \
        const bool up = (((tid << 3) + (ra)) & k) == 0;               \
        const float a_ = v[ra], b_ = v[rb];                           \
        v[ra] = up ? fminf(a_, b_) : fmaxf(a_, b_);                   \
        v[rb] = up ? fmaxf(a_, b_) : fminf(a_, b_);                   \
    }

#pragma unroll
    for (int kk = 1; kk <= 13; ++kk) {
        const int k = 1 << kk;

        // ---- cross-wave passes: j >= 512, via LDS ----
        for (int j = k >> 1; j >= 512; j >>= 1) {
#pragma unroll
            for (int r = 0; r < 8; ++r) s[(tid << 3) + r] = v[r];
            __syncthreads();
#pragma unroll
            for (int r = 0; r < 8; ++r) {
                const int i = (tid << 3) + r;
                const float pv = s[i ^ j];
                const bool amLow = (i & j) == 0;
                const bool up = (i & k) == 0;
                v[r] = (amLow == up) ? fminf(v[r], pv) : fmaxf(v[r], pv);
            }
            __syncthreads();
        }

        // ---- intra-wave passes: 8 <= j <= 256, via shuffle ----
        {
            const int jstart = ((k >> 1) > 256) ? 256 : (k >> 1);
            for (int j = jstart; j >= 8; j >>= 1) {
                const int m = j >> 3;                 // lane xor mask
                const bool amLow = (lane & m) == 0;
                const bool up = ((tid << 3) & k) == 0;   // k >= 16 here
#pragma unroll
                for (int r = 0; r < 8; ++r) {
                    const float pv = __shfl_xor(v[r], m, 64);
                    v[r] = (amLow == up) ? fminf(v[r], pv) : fmaxf(v[r], pv);
                }
            }
        }

        // ---- intra-thread passes: j in {4,2,1} (compile-time indices) ----
        if (k >= 8) {
            CEPAIR(0, 4) CEPAIR(1, 5) CEPAIR(2, 6) CEPAIR(3, 7)   // j=4
            CEPAIR(0, 2) CEPAIR(1, 3) CEPAIR(4, 6) CEPAIR(5, 7)   // j=2
            CEPAIR(0, 1) CEPAIR(2, 3) CEPAIR(4, 5) CEPAIR(6, 7)   // j=1
        } else if (k == 4) {
            CEPAIR(0, 2) CEPAIR(1, 3) CEPAIR(4, 6) CEPAIR(5, 7)   // j=2
            CEPAIR(0, 1) CEPAIR(2, 3) CEPAIR(4, 5) CEPAIR(6, 7)   // j=1
        } else {  // k == 2
            CEPAIR(0, 1) CEPAIR(2, 3) CEPAIR(4, 5) CEPAIR(6, 7)   // j=1
        }
    }
#undef CEPAIR

    // ---- per-thread local sums over the 8 sorted elements (in regs) ----
    double sx = 0.0, sx2 = 0.0;
#pragma unroll
    for (int r = 0; r < 8; ++r) {
        sx  += (double)v[r];
        sx2 += (double)v[r] * (double)v[r];
    }

    // ---- wave inclusive scan of sx; wave total of sx2 ----
    double ix = sx;
#pragma unroll
    for (int off = 1; off < 64; off <<= 1) {
        double t1 = __shfl_up(ix, off, 64);
        if (lane >= off) ix += t1;
    }
    double t2 = sx2;
#pragma unroll
    for (int off = 32; off > 0; off >>= 1) t2 += __shfl_xor(t2, off, 64);

    if (lane == 63) auxX[wv]  = ix;
    if (lane == 0)  auxT2[wv] = t2;
    __syncthreads();

    double wOff1 = 0.0, total1 = 0.0, total2 = 0.0;
#pragma unroll
    for (int w = 0; w < 16; ++w) {
        const double a1 = auxX[w];
        if (w < wv) wOff1 += a1;
        total1 += a1;
        total2 += auxT2[w];
    }
    const double exc1 = wOff1 + (ix - sx);   // exclusive prefix before this chunk
    const double nf = (double)N;

    // ---- on-the-fly h(k) evaluation + local argmax (== argmin obj) ----
    double run1 = exc1;
    double bestH = -1e300, bestCs = 0.0;
    int bestIdx = N;
#pragma unroll
    for (int r = 0; r < 8; ++r) {
        const int idx = (tid << 3) + r;
        run1 += (double)v[r];
        if (idx < N - 1) {
            const double kf  = (double)(idx + 1);
            const double rem = total1 - run1;
            const double h   = run1 * run1 * fastrcp(kf) +
                               rem  * rem  * fastrcp(nf - kf);
            if (h > bestH) { bestH = h; bestIdx = idx; bestCs = run1; }
        }
    }

    // ---- wave argmax reduce (max h, first index on ties) ----
#pragma unroll
    for (int off = 32; off > 0; off >>= 1) {
        const double oH   = __shfl_down(bestH, off, 64);
        const int    oIdx = __shfl_down(bestIdx, off, 64);
        const double oCs  = __shfl_down(bestCs, off, 64);
        if (oH > bestH || (oH == bestH && oIdx < bestIdx)) {
            bestH = oH; bestIdx = oIdx; bestCs = oCs;
        }
    }
    if (lane == 0) { redH[wv] = bestH; redIdx[wv] = bestIdx; redCs[wv] = bestCs; }
    __syncthreads();

    if (tid == 0) {
        double bH = redH[0], bCs = redCs[0];
        int bIdx = redIdx[0];
        for (int w = 1; w < 16; ++w) {
            if (redH[w] > bH || (redH[w] == bH && redIdx[w] < bIdx)) {
                bH = redH[w]; bIdx = redIdx[w]; bCs = redCs[w];
            }
        }
        const double Sb     = total2 - total1 * total1 / nf;
        const double optObj = (total2 - bH) / Sb;
        const double T      = (double)(bIdx + 1);
        out[0] = (float)(bCs / T + LAMB * optObj);
    }
}

// ---------------------------------------------------------------------------
extern "C" void kernel_launch(void* const* d_in, const int* in_sizes, int n_in,
                              void* d_out, int out_size, void* d_ws, size_t ws_size,
                              hipStream_t stream) {
    const float* inp = (const float*)d_in[0];
    const float* tgt = (const float*)d_in[1];
    float* errbuf = (float*)d_ws;   // 8192 f32 = 32 KB scratch

    rowerr_kernel<<<NROWS / 8, 256, 0, stream>>>(inp, tgt, errbuf);
    drae_kernel<<<1, 1024, 0, stream>>>(errbuf, (float*)d_out);
}